// Round 11
// baseline (115.905 us; speedup 1.0000x reference)
//
#include <hip/hip_runtime.h>
#include <stdint.h>

// MessagePassing R11: R10 + 2 column-tiles per wave (shared-B trick).
// A second k-shifted Wf A-frag (rows 8..14) lets ONE B-frag carry tile0's x
// in q0 lanes and tile1's x in q1 lanes: each A variant's zero rows annul the
// other tile's data. Stages 2/3 process both tiles in one unrolled region ->
// two independent ds_read->MFMA->tanh->ds_write chains interleave, hiding LDS
// latency (R10 was latency-bound at ~38 us, ~2.5x its issue floor).
// 128 cols/block, PSTR 132 (2-way banks, free), LDS 52.3 KB -> 3 blocks/CU,
// launch_bounds(256,3) -> VGPR cap ~170 (no spill).

#define NH 18
#define PSTR 132            // plane stride, dwords; 132%32=4 -> 2-way banks
#define NPL 99              // planes: 5 slots x 18 + 9 tail
#define TSCALE 2.8853900817779268f   // 2*log2(e), baked into A-frags
// LDS = 99*132*4 = 52272 B

typedef _Float16 half8 __attribute__((ext_vector_type(8)));
typedef __fp16 fp16x2 __attribute__((ext_vector_type(2)));
typedef float float4v __attribute__((ext_vector_type(4)));
union AB { uint32_t u[4]; half8 v; };

__device__ __forceinline__ float tanh_pre(float z) {
    // z pre-scaled by 2*log2(e): tanh = 1 - 2/(2^z + 1)
    float t = __builtin_amdgcn_exp2f(z);
    float r = __builtin_amdgcn_rcpf(t + 1.0f);
    return __builtin_fmaf(-2.0f, r, 1.0f);
}
__device__ __forceinline__ uint32_t pk2(float a, float b) {
    union { fp16x2 h; uint32_t u; } z;
    z.h = __builtin_amdgcn_cvt_pkrtz(a, b);
    return z.u;
}

// ---- prep: bake pre-scaled transposed A-frags into ws (12 frags) ----
// frag fi at dw fi*256 + ln*4: A[m=rt*16+(ln&15)][k=ks*32+(ln>>4)*8+j]
//  fi 0,1:  Wf^T rt (k<6 Wf, k==6 bf)
//  fi 2..5: Wm^T rt,ks (k<36 Wm, k==36 bm)
//  fi 6..9: WuFold^T rt,ks (k<18 Wu; 18..35 Wu+Wu[+18]; k==36 bu)
//  fi 10,11: Wf^T rt SHIFTED +8 (k-8<6 Wf, k-8==6 bf) -- tile1 stage-1 frags
__global__ __launch_bounds__(768) void prep_kernel(
    const float* __restrict__ Wf, const float* __restrict__ bf,
    const float* __restrict__ Wm, const float* __restrict__ bm,
    const float* __restrict__ Wu, const float* __restrict__ bu,
    uint32_t* __restrict__ ws)
{
    const int tid = threadIdx.x;
    const int fi = tid >> 6, ln = tid & 63;
    const int fq = ln >> 4, fl = ln & 15;
    int rt, ks, which;
    if (fi < 2)       { which = 0; rt = fi;            ks = 0; }
    else if (fi < 6)  { which = 1; rt = (fi - 2) >> 1; ks = (fi - 2) & 1; }
    else if (fi < 10) { which = 2; rt = (fi - 6) >> 1; ks = (fi - 6) & 1; }
    else              { which = 3; rt = fi - 10;       ks = 0; }
    const int m = rt * 16 + fl;
    for (int jp = 0; jp < 4; ++jp) {
        float vv[2];
        for (int hh = 0; hh < 2; ++hh) {
            int k = ks * 32 + fq * 8 + jp * 2 + hh;
            float val = 0.0f;
            if (m < NH) {
                if (which == 0) {
                    if (k < 6) val = Wf[k * NH + m];
                    else if (k == 6) val = bf[m];
                } else if (which == 1) {
                    if (k < 36) val = Wm[k * NH + m];
                    else if (k == 36) val = bm[m];
                } else if (which == 2) {
                    if (k < NH) val = Wu[k * NH + m];
                    else if (k < 36) val = Wu[k * NH + m] + Wu[(k + NH) * NH + m];
                    else if (k == 36) val = bu[m];
                } else {
                    int k2 = k - 8;
                    if (k2 >= 0 && k2 < 6) val = Wf[k2 * NH + m];
                    else if (k2 == 6) val = bf[m];
                }
            }
            vv[hh] = val * TSCALE;
        }
        ws[fi * 256 + ln * 4 + jp] = pk2(vv[0], vv[1]);
    }
}

#define MFMA16(A, Bv, Cv) __builtin_amdgcn_mfma_f32_16x16x32_f16((A).v, (Bv).v, (Cv), 0, 0, 0)

__global__ __launch_bounds__(256, 3) void mp_mfma(
    const float* __restrict__ x,
    const float* __restrict__ Wr, const float* __restrict__ br,
    const uint32_t* __restrict__ ws, float* __restrict__ out, int B)
{
    __shared__ uint32_t lds[NPL * PSTR];
    const int tid = threadIdx.x;
    const int lane = tid & 63, w = tid >> 6;
    const int l15 = lane & 15, q = lane >> 4;

    AB F[12];
    #pragma unroll
    for (int f = 0; f < 12; ++f) {
        const uint32_t* p = ws + f * 256 + lane * 4;
        F[f].u[0] = p[0]; F[f].u[1] = p[1]; F[f].u[2] = p[2]; F[f].u[3] = p[3];
    }

    const uint32_t ONE = 0x00003C00u;          // f16 (1.0, 0.0): bias row
    const float4v Z = {0.f, 0.f, 0.f, 0.f};

    const int c0 = w * 32 + l15;               // tile0 column; tile1 = c0+16
    const long long eg0 = (long long)blockIdx.x * 128 + c0;

    // shared x registers: q0 lanes hold tile0's x (k=0..6), q1 hold tile1's
    // (k=8..14). Bias 1.0 at k=6 (q0 u[3].lo) / k=14 (q1 u[3].lo): same ONE.
    uint32_t xpk[5][4];
    #pragma unroll
    for (int n = 0; n < 5; ++n) {
        xpk[n][0] = 0; xpk[n][1] = 0; xpk[n][2] = 0;
        xpk[n][3] = (q < 2) ? ONE : 0;
    }
    if (q < 2) {
        const long long eg = eg0 + q * 16;
        if (eg < (long long)B) {
            const float2* xp = (const float2*)x + eg * 15;
            #pragma unroll
            for (int n = 0; n < 5; ++n) {
                float2 a = xp[n * 3], b2 = xp[n * 3 + 1], d = xp[n * 3 + 2];
                xpk[n][0] = pk2(a.x, a.y); xpk[n][1] = pk2(b2.x, b2.y);
                xpk[n][2] = pk2(d.x, d.y);
            }
        }
    }
    const int qc0 = q * 4 * PSTR + c0;   // B-read term, tile0 (tile1: +16)
    const int qw0 = q * 2 * PSTR + c0;   // C-write term, tile0 (tile1: +16)

    // ---- stage 1: h_n = tanh([x_n|1] @ [Wf;bf]') for both tiles ----
    // h_n -> slot n first half (plane n*18) AND slot n-1 second half
    // ((n-1)*18+9; n=0 -> 81) AND (n==0) tail 90.
    #pragma unroll
    for (int n = 0; n < 5; ++n) {
        AB bx; bx.u[0] = xpk[n][0]; bx.u[1] = xpk[n][1];
               bx.u[2] = xpk[n][2]; bx.u[3] = xpk[n][3];
        const int P1 = n * 18;
        const int P2 = (n == 0) ? 81 : (n - 1) * 18 + 9;
        #pragma unroll
        for (int t = 0; t < 2; ++t) {
            float4v C0 = MFMA16(F[t ? 10 : 0], bx, Z);
            float4v C1 = MFMA16(F[t ? 11 : 1], bx, Z);
            const int qw = qw0 + t * 16, c = c0 + t * 16;
            uint32_t p0 = pk2(tanh_pre(C0[0]), tanh_pre(C0[1]));
            uint32_t p1 = pk2(tanh_pre(C0[2]), tanh_pre(C0[3]));
            uint32_t p2 = pk2(tanh_pre(C1[0]), tanh_pre(C1[1]));
            lds[P1 * PSTR + qw] = p0; lds[(P1 + 1) * PSTR + qw] = p1;
            lds[P2 * PSTR + qw] = p0; lds[(P2 + 1) * PSTR + qw] = p1;
            if (q == 0) { lds[(P1 + 8) * PSTR + c] = p2; lds[(P2 + 8) * PSTR + c] = p2; }
            if (n == 0) {
                lds[90 * PSTR + qw] = p0; lds[91 * PSTR + qw] = p1;
                if (q == 0) lds[98 * PSTR + c] = p2;
            }
        }
    }

    // ---- stage 2: M_n = tanh([h_n|h_{n+1}|1] @ [Wm;bm]') both tiles ----
    // reads slot n; M_n overwrites dead h_{n+1} copy (planes n*18+9..17);
    // per-column, program-ordered; tiles touch disjoint columns.
    #pragma unroll
    for (int n = 0; n < 5; ++n) {
        const int vb = n * 18;
        #pragma unroll
        for (int t = 0; t < 2; ++t) {
            const int qc = qc0 + t * 16, qw = qw0 + t * 16, c = c0 + t * 16;
            AB b0, b1;
            b0.u[0] = lds[vb * PSTR + qc];       b0.u[1] = lds[(vb + 1) * PSTR + qc];
            b0.u[2] = lds[(vb + 2) * PSTR + qc]; b0.u[3] = lds[(vb + 3) * PSTR + qc];
            b1.u[0] = lds[(vb + 16) * PSTR + c]; b1.u[1] = lds[(vb + 17) * PSTR + c];
            b1.u[2] = ONE; b1.u[3] = 0;
            float4v C0 = MFMA16(F[2], b0, Z); C0 = MFMA16(F[3], b1, C0);
            float4v C1 = MFMA16(F[4], b0, Z); C1 = MFMA16(F[5], b1, C1);
            uint32_t p0 = pk2(tanh_pre(C0[0]), tanh_pre(C0[1]));
            uint32_t p1 = pk2(tanh_pre(C0[2]), tanh_pre(C0[3]));
            uint32_t p2 = pk2(tanh_pre(C1[0]), tanh_pre(C1[1]));
            const int PM = n * 18 + 9;
            lds[PM * PSTR + qw] = p0; lds[(PM + 1) * PSTR + qw] = p1;
            if (q == 0) lds[(PM + 8) * PSTR + c] = p2;
        }
    }

    // readout tables (live only through stage 3; L1-hot)
    float wrA[5][4], wrB[5][2];
    #pragma unroll
    for (int n = 0; n < 5; ++n) {
        #pragma unroll
        for (int r = 0; r < 4; ++r) wrA[n][r] = Wr[n * NH + q * 4 + r];
        #pragma unroll
        for (int r = 0; r < 2; ++r) wrB[n][r] = (q == 0) ? Wr[n * NH + 16 + r] : 0.0f;
    }

    // ---- stage 3: U2_n = tanh([M_{n-1}|h_n|1] @ [WuFold;bu]'); readout ----
    // [M_{n-1}|h_n] contiguous at planes (n-1)*18+9 (n=0 -> 81..98).
    float rc[2] = {0.0f, 0.0f};
    #pragma unroll
    for (int n = 0; n < 5; ++n) {
        const int vb = (n == 0) ? 81 : (n - 1) * 18 + 9;
        #pragma unroll
        for (int t = 0; t < 2; ++t) {
            const int qc = qc0 + t * 16, c = c0 + t * 16;
            AB b0, b1;
            b0.u[0] = lds[vb * PSTR + qc];       b0.u[1] = lds[(vb + 1) * PSTR + qc];
            b0.u[2] = lds[(vb + 2) * PSTR + qc]; b0.u[3] = lds[(vb + 3) * PSTR + qc];
            b1.u[0] = lds[(vb + 16) * PSTR + c]; b1.u[1] = lds[(vb + 17) * PSTR + c];
            b1.u[2] = ONE; b1.u[3] = 0;
            float4v C0 = MFMA16(F[6], b0, Z); C0 = MFMA16(F[7], b1, C0);
            float4v C1 = MFMA16(F[8], b0, Z); C1 = MFMA16(F[9], b1, C1);
            rc[t] = __builtin_fmaf(tanh_pre(C0[0]), wrA[n][0], rc[t]);
            rc[t] = __builtin_fmaf(tanh_pre(C0[1]), wrA[n][1], rc[t]);
            rc[t] = __builtin_fmaf(tanh_pre(C0[2]), wrA[n][2], rc[t]);
            rc[t] = __builtin_fmaf(tanh_pre(C0[3]), wrA[n][3], rc[t]);
            rc[t] = __builtin_fmaf(tanh_pre(C1[0]), wrB[n][0], rc[t]);
            rc[t] = __builtin_fmaf(tanh_pre(C1[1]), wrB[n][1], rc[t]);
        }
    }

    // ---- readout: sum the 4 quads of each column; q0 stores both tiles ----
    #pragma unroll
    for (int t = 0; t < 2; ++t) {
        float s = rc[t];
        s += __shfl_xor(s, 16, 64);
        s += __shfl_xor(s, 32, 64);
        const long long eg = eg0 + t * 16;
        if (q == 0 && eg < (long long)B) out[eg] = s + br[0];
    }
}

extern "C" void kernel_launch(void* const* d_in, const int* in_sizes, int n_in,
                              void* d_out, int out_size, void* d_ws, size_t ws_size,
                              hipStream_t stream) {
    const float* x  = (const float*)d_in[0];
    const float* Wf = (const float*)d_in[1];
    const float* bf = (const float*)d_in[2];
    const float* Wm = (const float*)d_in[3];
    const float* bm = (const float*)d_in[4];
    const float* Wu = (const float*)d_in[5];
    const float* bu = (const float*)d_in[6];
    const float* Wr = (const float*)d_in[7];
    const float* br = (const float*)d_in[8];
    float* out = (float*)d_out;
    const int B = in_sizes[0] / 30;

    uint32_t* ws = (uint32_t*)d_ws;           // needs 12 KB; ws_size is ~MBs
    prep_kernel<<<1, 768, 0, stream>>>(Wf, bf, Wm, bm, Wu, bu, ws);
    const int grid = (B + 127) / 128;
    mp_mfma<<<grid, 256, 0, stream>>>(x, Wr, br, ws, out, B);
}

// Round 12
// 112.773 us; speedup vs baseline: 1.0278x; 1.0278x over previous
//
#include <hip/hip_runtime.h>
#include <stdint.h>

// MessagePassing R12: R10 base (1 tile/wave, 64 cols/block, PSTR 68, zero
// barriers) + occupancy 4->5 blocks/CU. R11's 2-tile ILP traded occupancy
// 16->12 waves/CU and lost; R10's 4 blocks/CU was self-imposed (LDS allows 5).
// launch_bounds(256,5) caps VGPR at 102; to fit WITHOUT spill (R7 lesson),
// frags are loaded per pipeline phase (stage1+2 up front, stage3 + readout
// tables during stage2) -> peak live ~80 regs vs R10's ~104.
// Tripwire: WRITE_SIZE must stay ~1 MB; >>1 MB means spill -> revert.

#define NH 18
#define PSTR 68             // plane stride, dwords; 68%32=4 -> 2-way banks (free)
#define NPL 99              // planes: 5 slots x 18 + 9 tail
#define TSCALE 2.8853900817779268f   // 2*log2(e), baked into A-frags
// LDS = 99*68*4 = 26928 B; x5 blocks = 134.6 KB <= 160 KB

typedef _Float16 half8 __attribute__((ext_vector_type(8)));
typedef __fp16 fp16x2 __attribute__((ext_vector_type(2)));
typedef float float4v __attribute__((ext_vector_type(4)));
union AB { uint32_t u[4]; half8 v; };

__device__ __forceinline__ float tanh_pre(float z) {
    // z pre-scaled by 2*log2(e): tanh = 1 - 2/(2^z + 1)
    float t = __builtin_amdgcn_exp2f(z);
    float r = __builtin_amdgcn_rcpf(t + 1.0f);
    return __builtin_fmaf(-2.0f, r, 1.0f);
}
__device__ __forceinline__ uint32_t pk2(float a, float b) {
    union { fp16x2 h; uint32_t u; } z;
    z.h = __builtin_amdgcn_cvt_pkrtz(a, b);
    return z.u;
}

// ---- prep: bake pre-scaled transposed A-frags (bias row k=36) into ws ----
// frag fi at dw fi*256 + ln*4: A[m=rt*16+(ln&15)][k=ks*32+(ln>>4)*8+j]
//  fi 0,1: Wf^T rt (k<6 Wf, k==6 bf); fi 2..5: Wm^T rt,ks (k==36 bm);
//  fi 6..9: WuFold^T rt,ks (k<18 Wu; 18..35 Wu+Wu[+18]; k==36 bu).
__global__ __launch_bounds__(640) void prep_kernel(
    const float* __restrict__ Wf, const float* __restrict__ bf,
    const float* __restrict__ Wm, const float* __restrict__ bm,
    const float* __restrict__ Wu, const float* __restrict__ bu,
    uint32_t* __restrict__ ws)
{
    const int tid = threadIdx.x;
    const int fi = tid >> 6, ln = tid & 63;
    const int fq = ln >> 4, fl = ln & 15;
    int rt, ks, which;
    if (fi < 2)      { which = 0; rt = fi;            ks = 0; }
    else if (fi < 6) { which = 1; rt = (fi - 2) >> 1; ks = (fi - 2) & 1; }
    else             { which = 2; rt = (fi - 6) >> 1; ks = (fi - 6) & 1; }
    const int m = rt * 16 + fl;
    for (int jp = 0; jp < 4; ++jp) {
        float vv[2];
        for (int hh = 0; hh < 2; ++hh) {
            int k = ks * 32 + fq * 8 + jp * 2 + hh;
            float val = 0.0f;
            if (m < NH) {
                if (which == 0) {
                    if (k < 6) val = Wf[k * NH + m];
                    else if (k == 6) val = bf[m];
                } else if (which == 1) {
                    if (k < 36) val = Wm[k * NH + m];
                    else if (k == 36) val = bm[m];
                } else {
                    if (k < NH) val = Wu[k * NH + m];
                    else if (k < 36) val = Wu[k * NH + m] + Wu[(k + NH) * NH + m];
                    else if (k == 36) val = bu[m];
                }
            }
            vv[hh] = val * TSCALE;
        }
        ws[fi * 256 + ln * 4 + jp] = pk2(vv[0], vv[1]);
    }
}

#define MFMA16(A, Bv, Cv) __builtin_amdgcn_mfma_f32_16x16x32_f16((A).v, (Bv).v, (Cv), 0, 0, 0)

__global__ __launch_bounds__(256, 5) void mp_mfma(
    const float* __restrict__ x,
    const float* __restrict__ Wr, const float* __restrict__ br,
    const uint32_t* __restrict__ ws, float* __restrict__ out, int B)
{
    __shared__ uint32_t lds[NPL * PSTR];
    const int tid = threadIdx.x;
    const int lane = tid & 63, w = tid >> 6;
    const int l15 = lane & 15, q = lane >> 4;

    // phase-1 frags only: stage1 (Ff) + stage2 (Fm). Stage3's frags and the
    // readout tables are loaded later to keep peak live regs under the
    // 102-VGPR cap of launch_bounds(256,5).
    AB Ff[2], Fm[4];
    #pragma unroll
    for (int f = 0; f < 2; ++f) {
        const uint32_t* p = ws + f * 256 + lane * 4;
        Ff[f].u[0] = p[0]; Ff[f].u[1] = p[1]; Ff[f].u[2] = p[2]; Ff[f].u[3] = p[3];
    }
    #pragma unroll
    for (int f = 0; f < 4; ++f) {
        const uint32_t* p = ws + (2 + f) * 256 + lane * 4;
        Fm[f].u[0] = p[0]; Fm[f].u[1] = p[1]; Fm[f].u[2] = p[2]; Fm[f].u[3] = p[3];
    }

    const uint32_t ONE = 0x00003C00u;          // f16 (1.0, 0.0): bias row
    const float4v Z = {0.f, 0.f, 0.f, 0.f};

    const int c = w * 16 + l15;                // column = element (wave-private)
    const long long eg = (long long)blockIdx.x * 64 + c;

    // x only on q==0 (B-rows k>=8 are A-zero-padded; explicit zeros, no junk)
    uint32_t xpk[5][4];
    #pragma unroll
    for (int n = 0; n < 5; ++n) {
        xpk[n][0] = 0; xpk[n][1] = 0; xpk[n][2] = 0;
        xpk[n][3] = (q == 0) ? ONE : 0;
    }
    if (q == 0 && eg < (long long)B) {
        const float2* xp = (const float2*)x + eg * 15;
        #pragma unroll
        for (int n = 0; n < 5; ++n) {
            float2 a = xp[n * 3], b2 = xp[n * 3 + 1], d = xp[n * 3 + 2];
            xpk[n][0] = pk2(a.x, a.y); xpk[n][1] = pk2(b2.x, b2.y);
            xpk[n][2] = pk2(d.x, d.y);
        }
    }
    const int qc = q * 4 * PSTR + c;   // B-read term (plane += q*4)
    const int qw = q * 2 * PSTR + c;   // C-write term (plane += q*2)

    // ---- stage 1: h_n = tanh([x_n|1] @ [Wf;bf]') ----
    // h_n -> slot n first half (plane n*18) AND slot n-1 second half
    // ((n-1)*18+9; n=0 -> 81) AND (n==0) tail 90.
    #pragma unroll
    for (int n = 0; n < 5; ++n) {
        AB bx; bx.u[0] = xpk[n][0]; bx.u[1] = xpk[n][1];
               bx.u[2] = xpk[n][2]; bx.u[3] = xpk[n][3];
        float4v C0 = MFMA16(Ff[0], bx, Z);
        float4v C1 = MFMA16(Ff[1], bx, Z);
        uint32_t p0 = pk2(tanh_pre(C0[0]), tanh_pre(C0[1]));
        uint32_t p1 = pk2(tanh_pre(C0[2]), tanh_pre(C0[3]));
        uint32_t p2 = pk2(tanh_pre(C1[0]), tanh_pre(C1[1]));
        const int P1 = n * 18;
        const int P2 = (n == 0) ? 81 : (n - 1) * 18 + 9;
        lds[P1 * PSTR + qw] = p0; lds[(P1 + 1) * PSTR + qw] = p1;
        lds[P2 * PSTR + qw] = p0; lds[(P2 + 1) * PSTR + qw] = p1;
        if (q == 0) { lds[(P1 + 8) * PSTR + c] = p2; lds[(P2 + 8) * PSTR + c] = p2; }
        if (n == 0) {
            lds[90 * PSTR + qw] = p0; lds[91 * PSTR + qw] = p1;
            if (q == 0) lds[98 * PSTR + c] = p2;
        }
    }

    // phase-2 loads issued here so their latency overlaps stage 2:
    // stage3 frags (Fu) + readout tables (L1-hot).
    AB Fu[4];
    #pragma unroll
    for (int f = 0; f < 4; ++f) {
        const uint32_t* p = ws + (6 + f) * 256 + lane * 4;
        Fu[f].u[0] = p[0]; Fu[f].u[1] = p[1]; Fu[f].u[2] = p[2]; Fu[f].u[3] = p[3];
    }
    float wrA[5][4], wrB[5][2];
    #pragma unroll
    for (int n = 0; n < 5; ++n) {
        #pragma unroll
        for (int r = 0; r < 4; ++r) wrA[n][r] = Wr[n * NH + q * 4 + r];
        #pragma unroll
        for (int r = 0; r < 2; ++r) wrB[n][r] = (q == 0) ? Wr[n * NH + 16 + r] : 0.0f;
    }

    // ---- stage 2: M_n = tanh([h_n|h_{n+1}|1] @ [Wm;bm]') ----
    // reads slot n (branch-free); M_n overwrites dead h_{n+1} copy at
    // planes n*18+9..17 (read-before-write, program-ordered per wave).
    #pragma unroll
    for (int n = 0; n < 5; ++n) {
        const int vb = n * 18;
        AB b0, b1;
        b0.u[0] = lds[vb * PSTR + qc];       b0.u[1] = lds[(vb + 1) * PSTR + qc];
        b0.u[2] = lds[(vb + 2) * PSTR + qc]; b0.u[3] = lds[(vb + 3) * PSTR + qc];
        b1.u[0] = lds[(vb + 16) * PSTR + c]; b1.u[1] = lds[(vb + 17) * PSTR + c];
        b1.u[2] = ONE; b1.u[3] = 0;
        float4v C0 = MFMA16(Fm[0], b0, Z); C0 = MFMA16(Fm[1], b1, C0);
        float4v C1 = MFMA16(Fm[2], b0, Z); C1 = MFMA16(Fm[3], b1, C1);
        uint32_t p0 = pk2(tanh_pre(C0[0]), tanh_pre(C0[1]));
        uint32_t p1 = pk2(tanh_pre(C0[2]), tanh_pre(C0[3]));
        uint32_t p2 = pk2(tanh_pre(C1[0]), tanh_pre(C1[1]));
        const int PM = n * 18 + 9;
        lds[PM * PSTR + qw] = p0; lds[(PM + 1) * PSTR + qw] = p1;
        if (q == 0) lds[(PM + 8) * PSTR + c] = p2;
    }

    // ---- stage 3: U2_n = tanh([M_{n-1}|h_n|1] @ [WuFold;bu]'); readout ----
    // [M_{n-1}|h_n] contiguous at planes (n-1)*18+9 (n=0 -> 81..98).
    float rc = 0.0f;
    #pragma unroll
    for (int n = 0; n < 5; ++n) {
        const int vb = (n == 0) ? 81 : (n - 1) * 18 + 9;
        AB b0, b1;
        b0.u[0] = lds[vb * PSTR + qc];       b0.u[1] = lds[(vb + 1) * PSTR + qc];
        b0.u[2] = lds[(vb + 2) * PSTR + qc]; b0.u[3] = lds[(vb + 3) * PSTR + qc];
        b1.u[0] = lds[(vb + 16) * PSTR + c]; b1.u[1] = lds[(vb + 17) * PSTR + c];
        b1.u[2] = ONE; b1.u[3] = 0;
        float4v C0 = MFMA16(Fu[0], b0, Z); C0 = MFMA16(Fu[1], b1, C0);
        float4v C1 = MFMA16(Fu[2], b0, Z); C1 = MFMA16(Fu[3], b1, C1);
        rc = __builtin_fmaf(tanh_pre(C0[0]), wrA[n][0], rc);
        rc = __builtin_fmaf(tanh_pre(C0[1]), wrA[n][1], rc);
        rc = __builtin_fmaf(tanh_pre(C0[2]), wrA[n][2], rc);
        rc = __builtin_fmaf(tanh_pre(C0[3]), wrA[n][3], rc);
        rc = __builtin_fmaf(tanh_pre(C1[0]), wrB[n][0], rc);
        rc = __builtin_fmaf(tanh_pre(C1[1]), wrB[n][1], rc);
    }

    // ---- readout: sum the 4 quads of each column ----
    float s = rc;
    s += __shfl_xor(s, 16, 64);
    s += __shfl_xor(s, 32, 64);
    if (q == 0 && eg < (long long)B) out[eg] = s + br[0];
}

extern "C" void kernel_launch(void* const* d_in, const int* in_sizes, int n_in,
                              void* d_out, int out_size, void* d_ws, size_t ws_size,
                              hipStream_t stream) {
    const float* x  = (const float*)d_in[0];
    const float* Wf = (const float*)d_in[1];
    const float* bf = (const float*)d_in[2];
    const float* Wm = (const float*)d_in[3];
    const float* bm = (const float*)d_in[4];
    const float* Wu = (const float*)d_in[5];
    const float* bu = (const float*)d_in[6];
    const float* Wr = (const float*)d_in[7];
    const float* br = (const float*)d_in[8];
    float* out = (float*)d_out;
    const int B = in_sizes[0] / 30;

    uint32_t* ws = (uint32_t*)d_ws;           // needs 10 KB; ws_size is ~MBs
    prep_kernel<<<1, 640, 0, stream>>>(Wf, bf, Wm, bm, Wu, bu, ws);
    const int grid = (B + 63) / 64;
    mp_mfma<<<grid, 256, 0, stream>>>(x, Wr, br, ws, out, B);
}

// Round 13
// 112.500 us; speedup vs baseline: 1.0303x; 1.0024x over previous
//
#include <hip/hip_runtime.h>
#include <stdint.h>

// MessagePassing R13: occupancy probe at the LDS limit. R11 (2-tile ILP) and
// R12 (5 blocks/CU) were both neutral -> either issue/pipe-bound (only op-count
// cuts help) or R12's VGPR cap silently spilled. R13 disambiguates: 6 blocks/CU
// (LDS 26.93KB x 6 = 161.6KB, exactly fits 160KiB; VGPR cap ~85) with a hard
// register diet: Fu frags + readout tables loaded AFTER stage 2 (live range
// only stage 3), xpk bias slot = 1 shared reg. Peak live ~70 regs.
// Outcomes: 104-108 bench = latency-bound, win; 110-114 = issue-bound, plateau;
// >=122 = spill, revert to (256,4).

#define NH 18
#define PSTR 68             // plane stride, dwords; 68%32=4 -> 2-way banks (free)
#define NPL 99              // planes: 5 slots x 18 + 9 tail
#define TSCALE 2.8853900817779268f   // 2*log2(e), baked into A-frags
// LDS = 99*68*4 = 26928 B; x6 blocks = 161568 B <= 163840 B

typedef _Float16 half8 __attribute__((ext_vector_type(8)));
typedef __fp16 fp16x2 __attribute__((ext_vector_type(2)));
typedef float float4v __attribute__((ext_vector_type(4)));
union AB { uint32_t u[4]; half8 v; };

__device__ __forceinline__ float tanh_pre(float z) {
    // z pre-scaled by 2*log2(e): tanh = 1 - 2/(2^z + 1)
    float t = __builtin_amdgcn_exp2f(z);
    float r = __builtin_amdgcn_rcpf(t + 1.0f);
    return __builtin_fmaf(-2.0f, r, 1.0f);
}
__device__ __forceinline__ uint32_t pk2(float a, float b) {
    union { fp16x2 h; uint32_t u; } z;
    z.h = __builtin_amdgcn_cvt_pkrtz(a, b);
    return z.u;
}

// ---- prep: bake pre-scaled transposed A-frags (bias row k=36) into ws ----
// frag fi at dw fi*256 + ln*4: A[m=rt*16+(ln&15)][k=ks*32+(ln>>4)*8+j]
//  fi 0,1: Wf^T rt (k<6 Wf, k==6 bf); fi 2..5: Wm^T rt,ks (k==36 bm);
//  fi 6..9: WuFold^T rt,ks (k<18 Wu; 18..35 Wu+Wu[+18]; k==36 bu).
__global__ __launch_bounds__(640) void prep_kernel(
    const float* __restrict__ Wf, const float* __restrict__ bf,
    const float* __restrict__ Wm, const float* __restrict__ bm,
    const float* __restrict__ Wu, const float* __restrict__ bu,
    uint32_t* __restrict__ ws)
{
    const int tid = threadIdx.x;
    const int fi = tid >> 6, ln = tid & 63;
    const int fq = ln >> 4, fl = ln & 15;
    int rt, ks, which;
    if (fi < 2)      { which = 0; rt = fi;            ks = 0; }
    else if (fi < 6) { which = 1; rt = (fi - 2) >> 1; ks = (fi - 2) & 1; }
    else             { which = 2; rt = (fi - 6) >> 1; ks = (fi - 6) & 1; }
    const int m = rt * 16 + fl;
    for (int jp = 0; jp < 4; ++jp) {
        float vv[2];
        for (int hh = 0; hh < 2; ++hh) {
            int k = ks * 32 + fq * 8 + jp * 2 + hh;
            float val = 0.0f;
            if (m < NH) {
                if (which == 0) {
                    if (k < 6) val = Wf[k * NH + m];
                    else if (k == 6) val = bf[m];
                } else if (which == 1) {
                    if (k < 36) val = Wm[k * NH + m];
                    else if (k == 36) val = bm[m];
                } else {
                    if (k < NH) val = Wu[k * NH + m];
                    else if (k < 36) val = Wu[k * NH + m] + Wu[(k + NH) * NH + m];
                    else if (k == 36) val = bu[m];
                }
            }
            vv[hh] = val * TSCALE;
        }
        ws[fi * 256 + ln * 4 + jp] = pk2(vv[0], vv[1]);
    }
}

#define MFMA16(A, Bv, Cv) __builtin_amdgcn_mfma_f32_16x16x32_f16((A).v, (Bv).v, (Cv), 0, 0, 0)

__global__ __launch_bounds__(256, 6) void mp_mfma(
    const float* __restrict__ x,
    const float* __restrict__ Wr, const float* __restrict__ br,
    const uint32_t* __restrict__ ws, float* __restrict__ out, int B)
{
    __shared__ uint32_t lds[NPL * PSTR];
    const int tid = threadIdx.x;
    const int lane = tid & 63, w = tid >> 6;
    const int l15 = lane & 15, q = lane >> 4;

    // phase-1 frags only: stage1 (Ff) + stage2 (Fm).
    AB Ff[2], Fm[4];
    #pragma unroll
    for (int f = 0; f < 2; ++f) {
        const uint32_t* p = ws + f * 256 + lane * 4;
        Ff[f].u[0] = p[0]; Ff[f].u[1] = p[1]; Ff[f].u[2] = p[2]; Ff[f].u[3] = p[3];
    }
    #pragma unroll
    for (int f = 0; f < 4; ++f) {
        const uint32_t* p = ws + (2 + f) * 256 + lane * 4;
        Fm[f].u[0] = p[0]; Fm[f].u[1] = p[1]; Fm[f].u[2] = p[2]; Fm[f].u[3] = p[3];
    }

    const uint32_t ONE = 0x00003C00u;          // f16 (1.0, 0.0): bias row
    const float4v Z = {0.f, 0.f, 0.f, 0.f};

    const int c = w * 16 + l15;                // column = element (wave-private)
    const long long eg = (long long)blockIdx.x * 64 + c;

    // x only on q==0 (B-rows k>=8 are A-zero-padded; explicit zeros, no junk).
    // Bias slot shared across n: one reg, not 5.
    const uint32_t xq3 = (q == 0) ? ONE : 0;
    uint32_t xpk[5][3];
    #pragma unroll
    for (int n = 0; n < 5; ++n) { xpk[n][0] = 0; xpk[n][1] = 0; xpk[n][2] = 0; }
    if (q == 0 && eg < (long long)B) {
        const float2* xp = (const float2*)x + eg * 15;
        #pragma unroll
        for (int n = 0; n < 5; ++n) {
            float2 a = xp[n * 3], b2 = xp[n * 3 + 1], d = xp[n * 3 + 2];
            xpk[n][0] = pk2(a.x, a.y); xpk[n][1] = pk2(b2.x, b2.y);
            xpk[n][2] = pk2(d.x, d.y);
        }
    }
    const int qc = q * 4 * PSTR + c;   // B-read term (plane += q*4)
    const int qw = q * 2 * PSTR + c;   // C-write term (plane += q*2)

    // ---- stage 1: h_n = tanh([x_n|1] @ [Wf;bf]') ----
    // h_n -> slot n first half (plane n*18) AND slot n-1 second half
    // ((n-1)*18+9; n=0 -> 81) AND (n==0) tail 90.
    #pragma unroll
    for (int n = 0; n < 5; ++n) {
        AB bx; bx.u[0] = xpk[n][0]; bx.u[1] = xpk[n][1];
               bx.u[2] = xpk[n][2]; bx.u[3] = xq3;
        float4v C0 = MFMA16(Ff[0], bx, Z);
        float4v C1 = MFMA16(Ff[1], bx, Z);
        uint32_t p0 = pk2(tanh_pre(C0[0]), tanh_pre(C0[1]));
        uint32_t p1 = pk2(tanh_pre(C0[2]), tanh_pre(C0[3]));
        uint32_t p2 = pk2(tanh_pre(C1[0]), tanh_pre(C1[1]));
        const int P1 = n * 18;
        const int P2 = (n == 0) ? 81 : (n - 1) * 18 + 9;
        lds[P1 * PSTR + qw] = p0; lds[(P1 + 1) * PSTR + qw] = p1;
        lds[P2 * PSTR + qw] = p0; lds[(P2 + 1) * PSTR + qw] = p1;
        if (q == 0) { lds[(P1 + 8) * PSTR + c] = p2; lds[(P2 + 8) * PSTR + c] = p2; }
        if (n == 0) {
            lds[90 * PSTR + qw] = p0; lds[91 * PSTR + qw] = p1;
            if (q == 0) lds[98 * PSTR + c] = p2;
        }
    }

    // ---- stage 2: M_n = tanh([h_n|h_{n+1}|1] @ [Wm;bm]') ----
    // reads slot n (branch-free); M_n overwrites dead h_{n+1} copy at
    // planes n*18+9..17 (read-before-write, program-ordered per wave).
    #pragma unroll
    for (int n = 0; n < 5; ++n) {
        const int vb = n * 18;
        AB b0, b1;
        b0.u[0] = lds[vb * PSTR + qc];       b0.u[1] = lds[(vb + 1) * PSTR + qc];
        b0.u[2] = lds[(vb + 2) * PSTR + qc]; b0.u[3] = lds[(vb + 3) * PSTR + qc];
        b1.u[0] = lds[(vb + 16) * PSTR + c]; b1.u[1] = lds[(vb + 17) * PSTR + c];
        b1.u[2] = ONE; b1.u[3] = 0;
        float4v C0 = MFMA16(Fm[0], b0, Z); C0 = MFMA16(Fm[1], b1, C0);
        float4v C1 = MFMA16(Fm[2], b0, Z); C1 = MFMA16(Fm[3], b1, C1);
        uint32_t p0 = pk2(tanh_pre(C0[0]), tanh_pre(C0[1]));
        uint32_t p1 = pk2(tanh_pre(C0[2]), tanh_pre(C0[3]));
        uint32_t p2 = pk2(tanh_pre(C1[0]), tanh_pre(C1[1]));
        const int PM = n * 18 + 9;
        lds[PM * PSTR + qw] = p0; lds[(PM + 1) * PSTR + qw] = p1;
        if (q == 0) lds[(PM + 8) * PSTR + c] = p2;
    }

    // phase-2 loads HERE (live only through stage 3 -> min register pressure
    // in stages 1-2; L2/L1-hot, latency hidden by 6 resident blocks).
    AB Fu[4];
    #pragma unroll
    for (int f = 0; f < 4; ++f) {
        const uint32_t* p = ws + (6 + f) * 256 + lane * 4;
        Fu[f].u[0] = p[0]; Fu[f].u[1] = p[1]; Fu[f].u[2] = p[2]; Fu[f].u[3] = p[3];
    }
    float wrA[5][4], wrB[5][2];
    #pragma unroll
    for (int n = 0; n < 5; ++n) {
        #pragma unroll
        for (int r = 0; r < 4; ++r) wrA[n][r] = Wr[n * NH + q * 4 + r];
        #pragma unroll
        for (int r = 0; r < 2; ++r) wrB[n][r] = (q == 0) ? Wr[n * NH + 16 + r] : 0.0f;
    }

    // ---- stage 3: U2_n = tanh([M_{n-1}|h_n|1] @ [WuFold;bu]'); readout ----
    // [M_{n-1}|h_n] contiguous at planes (n-1)*18+9 (n=0 -> 81..98).
    float rc = 0.0f;
    #pragma unroll
    for (int n = 0; n < 5; ++n) {
        const int vb = (n == 0) ? 81 : (n - 1) * 18 + 9;
        AB b0, b1;
        b0.u[0] = lds[vb * PSTR + qc];       b0.u[1] = lds[(vb + 1) * PSTR + qc];
        b0.u[2] = lds[(vb + 2) * PSTR + qc]; b0.u[3] = lds[(vb + 3) * PSTR + qc];
        b1.u[0] = lds[(vb + 16) * PSTR + c]; b1.u[1] = lds[(vb + 17) * PSTR + c];
        b1.u[2] = ONE; b1.u[3] = 0;
        float4v C0 = MFMA16(Fu[0], b0, Z); C0 = MFMA16(Fu[1], b1, C0);
        float4v C1 = MFMA16(Fu[2], b0, Z); C1 = MFMA16(Fu[3], b1, C1);
        rc = __builtin_fmaf(tanh_pre(C0[0]), wrA[n][0], rc);
        rc = __builtin_fmaf(tanh_pre(C0[1]), wrA[n][1], rc);
        rc = __builtin_fmaf(tanh_pre(C0[2]), wrA[n][2], rc);
        rc = __builtin_fmaf(tanh_pre(C0[3]), wrA[n][3], rc);
        rc = __builtin_fmaf(tanh_pre(C1[0]), wrB[n][0], rc);
        rc = __builtin_fmaf(tanh_pre(C1[1]), wrB[n][1], rc);
    }

    // ---- readout: sum the 4 quads of each column ----
    float s = rc;
    s += __shfl_xor(s, 16, 64);
    s += __shfl_xor(s, 32, 64);
    if (q == 0 && eg < (long long)B) out[eg] = s + br[0];
}

extern "C" void kernel_launch(void* const* d_in, const int* in_sizes, int n_in,
                              void* d_out, int out_size, void* d_ws, size_t ws_size,
                              hipStream_t stream) {
    const float* x  = (const float*)d_in[0];
    const float* Wf = (const float*)d_in[1];
    const float* bf = (const float*)d_in[2];
    const float* Wm = (const float*)d_in[3];
    const float* bm = (const float*)d_in[4];
    const float* Wu = (const float*)d_in[5];
    const float* bu = (const float*)d_in[6];
    const float* Wr = (const float*)d_in[7];
    const float* br = (const float*)d_in[8];
    float* out = (float*)d_out;
    const int B = in_sizes[0] / 30;

    uint32_t* ws = (uint32_t*)d_ws;           // needs 10 KB; ws_size is ~MBs
    prep_kernel<<<1, 640, 0, stream>>>(Wf, bf, Wm, bm, Wu, bu, ws);
    const int grid = (B + 63) / 64;
    mp_mfma<<<grid, 256, 0, stream>>>(x, Wr, br, ws, out, B);
}